// Round 8
// baseline (349.895 us; speedup 1.0000x reference)
//
#include <hip/hip_runtime.h>

#define HID 128
#define NNODE 10000
#define KN 16
#define ROWS 80000    // BATCH * NNODE
#define NTILES 2500   // ROWS / 32
#define ANCH 313      // ceil(NNODE/32) aggr3 row-chunks (fallback)

typedef __attribute__((ext_vector_type(8))) short short8;   // 8 bf16 (4 VGPRs)
typedef __attribute__((ext_vector_type(4))) float f32x4;
typedef __attribute__((ext_vector_type(2))) float f32x2;
typedef __attribute__((ext_vector_type(4))) int i32x4;
typedef __attribute__((ext_vector_type(4))) unsigned int u32x4;
typedef __attribute__((ext_vector_type(2))) unsigned int u32x2;

__device__ __forceinline__ unsigned short f2b(float f) {
    unsigned u = __float_as_uint(f);
    u += 0x7FFFu + ((u >> 16) & 1u);       // round-to-nearest-even
    return (unsigned short)(u >> 16);
}

// Weight transpose+convert, all variants in one launch (188416 outputs).
// Wt384[n][k]: k<128 -> Wu[k] (for Gs), 128-255 -> Wu[k-128] (for Gi),
//              256-383 -> Wu[k-128] (h rows 128..255).
__global__ __launch_bounds__(256) void wconv_all(
    const float* __restrict__ W1, const float* __restrict__ W2,
    const float* __restrict__ Wu1, const float* __restrict__ Wu2,
    unsigned short* __restrict__ W1t, unsigned short* __restrict__ W2t,
    unsigned short* __restrict__ Wu1t3, unsigned short* __restrict__ Wu2t3,
    unsigned short* __restrict__ Wu1t2, unsigned short* __restrict__ Wu2t2) {
    int idx = blockIdx.x * 256 + threadIdx.x;   // < 188416
    if (idx < 8192) {
        int n = idx & 127, k = idx >> 7;
        W1t[n * 64 + k] = f2b(W1[k * 128 + n]);
    } else if (idx < 24576) {
        int off = idx - 8192; int n = off & 127, k = off >> 7;
        W2t[n * 128 + k] = f2b(W2[k * 128 + n]);
    } else if (idx < 73728) {
        int off = idx - 24576; int n = off % 128, k = off / 128;   // k<384
        int sr = k < 256 ? (k & 127) : (k - 128);
        Wu1t3[n * 384 + k] = f2b(Wu1[sr * 128 + n]);
    } else if (idx < 122880) {
        int off = idx - 73728; int n = off % 128, k = off / 128;
        int sr = k < 256 ? (k & 127) : (k - 128);
        Wu2t3[n * 384 + k] = f2b(Wu2[sr * 128 + n]);
    } else if (idx < 155648) {
        int off = idx - 122880; int n = off & 127, k = off >> 7;
        Wu1t2[n * 256 + k] = f2b(Wu1[k * 128 + n]);
    } else {
        int off = idx - 155648; int n = off & 127, k = off >> 7;
        Wu2t2[n * 256 + k] = f2b(Wu2[k * 128 + n]);
    }
}

// Embed: Y[r][:] = relu(X[r][:] @ W + b), transposed-operand MFMA,
// persistent W-frags, grid-stride, 2-deep x pipeline. (unchanged from R7)
template<int K, bool AF32>
__global__ __launch_bounds__(512) void embed2(
    const void* __restrict__ A0, const void* __restrict__ A1,
    const unsigned short* __restrict__ Wt, const float* __restrict__ bias,
    unsigned short* __restrict__ Y0, unsigned short* __restrict__ Y1, int tot) {
    const int t = threadIdx.x, w = t >> 6, lane = t & 63;
    const int lrow = lane & 15, lk = lane >> 4;
    const int rs = w & 1, ng = w >> 1;
    const int col0 = ng * 32;

    short8 wf[2][K / 32];
    f32x4 bv[2];
#pragma unroll
    for (int p = 0; p < 2; ++p) {
        bv[p] = *(const f32x4*)(bias + col0 + p * 16 + lk * 4);
#pragma unroll
        for (int kt = 0; kt < K / 32; ++kt)
            wf[p][kt] = *(const short8*)(Wt + (col0 + p * 16 + lrow) * K + kt * 32 + lk * 8);
    }

    int T = blockIdx.x;
    if (T >= tot) return;

    auto loadx = [&](int TT, short8* xf) {
        const int half = TT >= NTILES;
        const void* A = half ? A1 : A0;
        const int row = (TT - half * NTILES) * 32 + rs * 16 + lrow;
        if constexpr (AF32) {
            const float* X = (const float*)A + (size_t)row * K;
#pragma unroll
            for (int kt = 0; kt < K / 32; ++kt) {
                f32x4 f0 = *(const f32x4*)(X + kt * 32 + lk * 8);
                f32x4 f1 = *(const f32x4*)(X + kt * 32 + lk * 8 + 4);
                short8 v;
#pragma unroll
                for (int e = 0; e < 4; ++e) { v[e] = (short)f2b(f0[e]); v[4 + e] = (short)f2b(f1[e]); }
                xf[kt] = v;
            }
        } else {
            const unsigned short* X = (const unsigned short*)A + (size_t)row * K;
#pragma unroll
            for (int kt = 0; kt < K / 32; ++kt)
                xf[kt] = *(const short8*)(X + kt * 32 + lk * 8);
        }
    };

    short8 xf[K / 32], xn[K / 32];
    loadx(T, xf);
    for (;;) {
        const int Tn = T + gridDim.x;
        const bool more = Tn < tot;
        if (more) loadx(Tn, xn);

        const int half = T >= NTILES;
        unsigned short* Y = half ? Y1 : Y0;
        const int row = (T - half * NTILES) * 32 + rs * 16 + lrow;
#pragma unroll
        for (int p = 0; p < 2; ++p) {
            f32x4 acc = {0.f, 0.f, 0.f, 0.f};
#pragma unroll
            for (int kt = 0; kt < K / 32; ++kt)
                acc = __builtin_amdgcn_mfma_f32_16x16x32_bf16(wf[p][kt], xf[kt], acc, 0, 0, 0);
            float v0 = acc[0] + bv[p][0]; v0 = v0 > 0.f ? v0 : 0.f;
            float v1 = acc[1] + bv[p][1]; v1 = v1 > 0.f ? v1 : 0.f;
            float v2 = acc[2] + bv[p][2]; v2 = v2 > 0.f ? v2 : 0.f;
            float v3 = acc[3] + bv[p][3]; v3 = v3 > 0.f ? v3 : 0.f;
            u32x2 ov = {(unsigned)f2b(v0) | ((unsigned)f2b(v1) << 16),
                        (unsigned)f2b(v2) | ((unsigned)f2b(v3) << 16)};
            *(u32x2*)(Y + (size_t)row * HID + col0 + p * 16 + lk * 4) = ov;
        }
        if (!more) break;
#pragma unroll
        for (int kt = 0; kt < K / 32; ++kt) xf[kt] = xn[kt];
        T = Tn;
    }
}

// aggr4: LDS-source-staged gather. One block per (tensor, b, 8-col slice):
// stage SRC[b, 0:NNODE, c0:c0+8] (160 KB) into LDS, then per dest row
// sum 16 neighbor rows read from LDS. Partials: tensor 0 -> Gs, 1 -> Gi.
__global__ __launch_bounds__(1024) void aggr4(
    const unsigned short* __restrict__ SE, const unsigned short* __restrict__ IE,
    const int* __restrict__ sidx, const int* __restrict__ iidx,
    unsigned short* __restrict__ Gs, unsigned short* __restrict__ Gi) {
    __shared__ __align__(16) unsigned short slice[NNODE * 8];   // 160,000 B
    const int t = threadIdx.x;
    const int colblk = blockIdx.x & 15;
    const int b = (blockIdx.x >> 4) & 7;
    const int tensor = blockIdx.x >> 7;
    const int c0 = colblk * 8;
    const unsigned short* SRC = tensor ? IE : SE;
    const int* IDX = tensor ? iidx : sidx;
    unsigned short* G = tensor ? Gi : Gs;
    const size_t base = (size_t)b * NNODE * HID;

    // ---- stage: strided 16 B per node (conflict-free linear LDS writes)
    for (int i = t; i < NNODE; i += 1024)
        *(short8*)(slice + i * 8) = *(const short8*)(SRC + base + (size_t)i * HID + c0);
    __syncthreads();

    // ---- gather from LDS
    for (int r = t; r < NNODE; r += 1024) {
        int id[KN];
#pragma unroll
        for (int q = 0; q < 4; ++q) {
            i32x4 i4 = *(const i32x4*)(IDX + (size_t)r * KN + q * 4);
#pragma unroll
            for (int j = 0; j < 4; ++j) id[q * 4 + j] = i4[j];
        }
        f32x2 acc[4];
#pragma unroll
        for (int w = 0; w < 4; ++w) acc[w] = (f32x2){0.f, 0.f};
#pragma unroll
        for (int j = 0; j < KN; ++j) {
            u32x4 u = *(const u32x4*)(slice + id[j] * 8);
#pragma unroll
            for (int w = 0; w < 4; ++w)
                acc[w] += (f32x2){__uint_as_float(u[w] << 16),
                                  __uint_as_float(u[w] & 0xffff0000u)};
        }
        u32x4 ov = {(unsigned)f2b(acc[0].x) | ((unsigned)f2b(acc[0].y) << 16),
                    (unsigned)f2b(acc[1].x) | ((unsigned)f2b(acc[1].y) << 16),
                    (unsigned)f2b(acc[2].x) | ((unsigned)f2b(acc[2].y) << 16),
                    (unsigned)f2b(acc[3].x) | ((unsigned)f2b(acc[3].y) << 16)};
        *(u32x4*)(G + base + (size_t)r * HID + c0) = ov;
    }
}

// update K=384: Y = relu([Gs|Gi|H] @ Wut384^T + bu) — the Gs+Gi sum happens
// inside the MFMA via duplicated aggr weight rows. Persistent W, grid-stride.
__global__ __launch_bounds__(512) void update_gemm3(
    const unsigned short* __restrict__ Gs, const unsigned short* __restrict__ Gi,
    const unsigned short* __restrict__ H,
    const unsigned short* __restrict__ Wut, const float* __restrict__ bu,
    float* __restrict__ Yf, unsigned short* __restrict__ Yb, int writeb) {
    const int t = threadIdx.x, w = t >> 6, lane = t & 63;
    const int lrow = lane & 15, lk = lane >> 4;
    const int rs = w & 1, ng = w >> 1;
    const int col0 = ng * 32;

    short8 wf[2][12];
    f32x4 bv[2];
#pragma unroll
    for (int p = 0; p < 2; ++p) {
        bv[p] = *(const f32x4*)(bu + col0 + p * 16 + lk * 4);
#pragma unroll
        for (int kt = 0; kt < 12; ++kt)
            wf[p][kt] = *(const short8*)(Wut + (col0 + p * 16 + lrow) * 384 + kt * 32 + lk * 8);
    }

    for (int T = blockIdx.x; T < NTILES; T += gridDim.x) {
        const int row = T * 32 + rs * 16 + lrow;
        short8 xf[12];
#pragma unroll
        for (int kt = 0; kt < 4; ++kt) {
            xf[kt]     = *(const short8*)(Gs + (size_t)row * HID + kt * 32 + lk * 8);
            xf[4 + kt] = *(const short8*)(Gi + (size_t)row * HID + kt * 32 + lk * 8);
            xf[8 + kt] = *(const short8*)(H  + (size_t)row * HID + kt * 32 + lk * 8);
        }
#pragma unroll
        for (int p = 0; p < 2; ++p) {
            f32x4 acc = {0.f, 0.f, 0.f, 0.f};
#pragma unroll
            for (int kt = 0; kt < 12; ++kt)
                acc = __builtin_amdgcn_mfma_f32_16x16x32_bf16(wf[p][kt], xf[kt], acc, 0, 0, 0);
            f32x4 o;
#pragma unroll
            for (int j = 0; j < 4; ++j) {
                float v = acc[j] + bv[p][j];
                o[j] = v > 0.f ? v : 0.f;
            }
            *(f32x4*)(Yf + (size_t)row * HID + col0 + p * 16 + lk * 4) = o;
            if (writeb) {
                u32x2 ov = {(unsigned)f2b(o[0]) | ((unsigned)f2b(o[1]) << 16),
                            (unsigned)f2b(o[2]) | ((unsigned)f2b(o[3]) << 16)};
                *(u32x2*)(Yb + (size_t)row * HID + col0 + p * 16 + lk * 4) = ov;
            }
        }
    }
}

// ---------------- fallback kernels (R7, small-ws path) ----------------
__global__ __launch_bounds__(512) void aggr3(
    const unsigned short* __restrict__ SE, const unsigned short* __restrict__ IE,
    const int* __restrict__ sidx, const int* __restrict__ iidx,
    unsigned short* __restrict__ G) {
    __shared__ int sh[32][33];
    const int t = threadIdx.x;
    const int b = blockIdx.x & 7;
    const int hc = blockIdx.x >> 3;
    const int h = hc >= ANCH ? 1 : 0;
    const int c = hc - h * ANCH;
    const int n0 = c * 32;

#pragma unroll
    for (int q = 0; q < 2; ++q) {
        const int e = t + q * 512;
        const int r = e >> 5, k = e & 31;
        int nr = n0 + r; if (nr > NNODE - 1) nr = NNODE - 1;
        sh[r][k] = (k < KN) ? sidx[nr * KN + k] : iidx[nr * KN + (k - KN)];
    }
    __syncthreads();

    const int r = t >> 4, p = t & 15;
    const int col0 = h * 64 + p * 4;
    const int n = n0 + r;
    const size_t base = (size_t)b * NNODE * HID + col0;

    u32x2 vs[16], vi[16];
#pragma unroll
    for (int j = 0; j < 16; ++j)
        vs[j] = *(const u32x2*)(SE + base + (size_t)sh[r][j] * HID);
#pragma unroll
    for (int j = 0; j < 16; ++j)
        vi[j] = *(const u32x2*)(IE + base + (size_t)sh[r][16 + j] * HID);

    f32x2 a0 = {0.f, 0.f}, a1 = {0.f, 0.f};
#pragma unroll
    for (int j = 0; j < 16; ++j) {
        unsigned u0 = vs[j][0], u1 = vs[j][1];
        a0 += (f32x2){__uint_as_float(u0 << 16), __uint_as_float(u0 & 0xffff0000u)};
        a1 += (f32x2){__uint_as_float(u1 << 16), __uint_as_float(u1 & 0xffff0000u)};
    }
#pragma unroll
    for (int j = 0; j < 16; ++j) {
        unsigned u0 = vi[j][0], u1 = vi[j][1];
        a0 += (f32x2){__uint_as_float(u0 << 16), __uint_as_float(u0 & 0xffff0000u)};
        a1 += (f32x2){__uint_as_float(u1 << 16), __uint_as_float(u1 & 0xffff0000u)};
    }

    if (n < NNODE) {
        u32x2 ov = {(unsigned)f2b(a0.x) | ((unsigned)f2b(a0.y) << 16),
                    (unsigned)f2b(a1.x) | ((unsigned)f2b(a1.y) << 16)};
        *(u32x2*)(G + ((size_t)b * NNODE + n) * HID + col0) = ov;
    }
}

__global__ __launch_bounds__(512) void update_gemm2(
    const unsigned short* __restrict__ G, const unsigned short* __restrict__ H,
    const unsigned short* __restrict__ Wut, const float* __restrict__ bu,
    float* __restrict__ Yf, unsigned short* __restrict__ Yb, int writeb) {
    const int t = threadIdx.x, w = t >> 6, lane = t & 63;
    const int lrow = lane & 15, lk = lane >> 4;
    const int rs = w & 1, ng = w >> 1;
    const int col0 = ng * 32;

    short8 wf[2][8];
    f32x4 bv[2];
#pragma unroll
    for (int p = 0; p < 2; ++p) {
        bv[p] = *(const f32x4*)(bu + col0 + p * 16 + lk * 4);
#pragma unroll
        for (int kt = 0; kt < 8; ++kt)
            wf[p][kt] = *(const short8*)(Wut + (col0 + p * 16 + lrow) * 256 + kt * 32 + lk * 8);
    }

    for (int T = blockIdx.x; T < NTILES; T += gridDim.x) {
        const int row = T * 32 + rs * 16 + lrow;
        short8 xf[8];
#pragma unroll
        for (int kt = 0; kt < 4; ++kt) {
            xf[kt]     = *(const short8*)(G + (size_t)row * HID + kt * 32 + lk * 8);
            xf[4 + kt] = *(const short8*)(H + (size_t)row * HID + kt * 32 + lk * 8);
        }
#pragma unroll
        for (int p = 0; p < 2; ++p) {
            f32x4 acc = {0.f, 0.f, 0.f, 0.f};
#pragma unroll
            for (int kt = 0; kt < 8; ++kt)
                acc = __builtin_amdgcn_mfma_f32_16x16x32_bf16(wf[p][kt], xf[kt], acc, 0, 0, 0);
            f32x4 o;
#pragma unroll
            for (int j = 0; j < 4; ++j) {
                float v = acc[j] + bv[p][j];
                o[j] = v > 0.f ? v : 0.f;
            }
            *(f32x4*)(Yf + (size_t)row * HID + col0 + p * 16 + lk * 4) = o;
            if (writeb) {
                u32x2 ov = {(unsigned)f2b(o[0]) | ((unsigned)f2b(o[1]) << 16),
                            (unsigned)f2b(o[2]) | ((unsigned)f2b(o[3]) << 16)};
                *(u32x2*)(Yb + (size_t)row * HID + col0 + p * 16 + lk * 4) = ov;
            }
        }
    }
}

extern "C" void kernel_launch(void* const* d_in, const int* in_sizes, int n_in,
                              void* d_out, int out_size, void* d_ws, size_t ws_size,
                              hipStream_t stream) {
    const float* state    = (const float*)d_in[0];
    const float* internal = (const float*)d_in[1];
    const int*   sidx     = (const int*)d_in[2];
    const int*   iidx     = (const int*)d_in[3];
    const float* W1  = (const float*)d_in[4];
    const float* b1  = (const float*)d_in[5];
    const float* W2  = (const float*)d_in[6];
    const float* b2  = (const float*)d_in[7];
    const float* Wu1 = (const float*)d_in[8];
    const float* bu1 = (const float*)d_in[9];
    const float* Wu2 = (const float*)d_in[10];
    const float* bu2 = (const float*)d_in[11];

    float* hu1 = (float*)d_out;
    float* hu2 = hu1 + (size_t)ROWS * HID;

    unsigned short* W1t   = (unsigned short*)d_ws;        // 8192
    unsigned short* W2t   = W1t + 8192;                   // 16384
    unsigned short* Wu1t3 = W2t + 16384;                  // 49152 (K=384)
    unsigned short* Wu2t3 = Wu1t3 + 49152;                // 49152
    unsigned short* Wu1t2 = Wu2t3 + 49152;                // 32768 (K=256, fallback)
    unsigned short* Wu2t2 = Wu1t2 + 32768;                // 32768
    unsigned short* bufA  = Wu2t2 + 32768;                // weights total 188416
    unsigned short* bufB  = bufA + (size_t)ROWS * HID;    // 10,240,000 elems each
    unsigned short* bufC  = bufB + (size_t)ROWS * HID;
    unsigned short* bufD  = bufC + (size_t)ROWS * HID;
    unsigned short* bufE  = bufD + (size_t)ROWS * HID;

    const size_t need_big = ((size_t)188416 + 5 * (size_t)ROWS * HID) * 2;
    const bool big = ws_size >= need_big;

    dim3 b256(256), b512(512), b1024(1024);

    wconv_all<<<736, b256, 0, stream>>>(W1, W2, Wu1, Wu2,
                                        W1t, W2t, Wu1t3, Wu2t3, Wu1t2, Wu2t2);

    // layer-1 embeddings: SE1 -> bufA, IE1 -> bufB
    embed2<64, true><<<1250, b512, 0, stream>>>(state, internal, W1t, b1, bufA, bufB, 2 * NTILES);

    if (big) {
        // layer 1: partial aggregates Gs->bufD, Gi->bufE; hu1 -> d_out + bufC
        aggr4<<<256, b1024, 0, stream>>>(bufA, bufB, sidx, iidx, bufD, bufE);
        update_gemm3<<<1250, b512, 0, stream>>>(bufD, bufE, bufB, Wu1t3, bu1, hu1, bufC, 1);
        // layer 2 embeds: se2 = relu(SE1@W2) -> bufD, ie2 = relu(hu1b@W2) -> bufE
        embed2<128, false><<<1250, b512, 0, stream>>>(bufA, bufC, W2t, b2, bufD, bufE, 2 * NTILES);
        // layer 2: Gs->bufA, Gi->bufB; hu2 -> d_out
        aggr4<<<256, b1024, 0, stream>>>(bufD, bufE, sidx, iidx, bufA, bufB);
        update_gemm3<<<1250, b512, 0, stream>>>(bufA, bufB, bufE, Wu2t3, bu2, hu2, nullptr, 0);
    } else {
        // 3-buffer fallback (R7 path): hu2 region doubles as bf16 G scratch.
        unsigned short* Ghu2 = (unsigned short*)hu2;
        const int AGRID = 8 * 2 * ANCH;
        aggr3<<<AGRID, b512, 0, stream>>>(bufA, bufB, sidx, iidx, Ghu2);
        update_gemm2<<<1250, b512, 0, stream>>>(Ghu2, bufB, Wu1t2, bu1, hu1, bufC, 1);
        embed2<128, false><<<1250, b512, 0, stream>>>(bufA, nullptr, W2t, b2, bufB, nullptr, NTILES);
        embed2<128, false><<<1250, b512, 0, stream>>>(bufC, nullptr, W2t, b2, bufA, nullptr, NTILES);
        aggr3<<<AGRID, b512, 0, stream>>>(bufB, bufA, sidx, iidx, bufC);
        update_gemm2<<<1250, b512, 0, stream>>>(bufC, bufA, Wu2t2, bu2, hu2, nullptr, 0);
    }
}

// Round 9
// 242.987 us; speedup vs baseline: 1.4400x; 1.4400x over previous
//
#include <hip/hip_runtime.h>

#define HID 128
#define NNODE 10000
#define KN 16
#define ROWS 80000    // BATCH * NNODE
#define NTILES 2500   // ROWS / 32

typedef __attribute__((ext_vector_type(8))) short short8;   // 8 bf16 (4 VGPRs)
typedef __attribute__((ext_vector_type(4))) float f32x4;
typedef __attribute__((ext_vector_type(2))) unsigned int u32x2;

__device__ __forceinline__ unsigned short f2b(float f) {
    unsigned u = __float_as_uint(f);
    u += 0x7FFFu + ((u >> 16) & 1u);       // round-to-nearest-even
    return (unsigned short)(u >> 16);
}

// All four weight transposes+converts in one launch.
__global__ __launch_bounds__(256) void wconv_all(
    const float* __restrict__ W1, const float* __restrict__ W2,
    const float* __restrict__ Wu1, const float* __restrict__ Wu2,
    unsigned short* __restrict__ W1t, unsigned short* __restrict__ W2t,
    unsigned short* __restrict__ Wu1t, unsigned short* __restrict__ Wu2t) {
    int idx = blockIdx.x * 256 + threadIdx.x;   // < 90112
    const float* W; unsigned short* Wt; int K; int off;
    if (idx < 8192)       { W = W1;  Wt = W1t;  K = 64;  off = idx; }
    else if (idx < 24576) { W = W2;  Wt = W2t;  K = 128; off = idx - 8192; }
    else if (idx < 57344) { W = Wu1; Wt = Wu1t; K = 256; off = idx - 24576; }
    else                  { W = Wu2; Wt = Wu2t; K = 256; off = idx - 57344; }
    int n = off & 127, k = off >> 7;
    Wt[n * K + k] = f2b(W[off]);
}

// Embed: Y[r][:] = relu(X[r][:] @ W + b), transposed-operand MFMA,
// persistent W-frags, grid-stride, 2-deep x pipeline.
template<int K, bool AF32>
__global__ __launch_bounds__(512) void embed2(
    const void* __restrict__ A0, const void* __restrict__ A1,
    const unsigned short* __restrict__ Wt, const float* __restrict__ bias,
    unsigned short* __restrict__ Y0, unsigned short* __restrict__ Y1, int tot) {
    const int t = threadIdx.x, w = t >> 6, lane = t & 63;
    const int lrow = lane & 15, lk = lane >> 4;
    const int rs = w & 1, ng = w >> 1;
    const int col0 = ng * 32;

    short8 wf[2][K / 32];
    f32x4 bv[2];
#pragma unroll
    for (int p = 0; p < 2; ++p) {
        bv[p] = *(const f32x4*)(bias + col0 + p * 16 + lk * 4);
#pragma unroll
        for (int kt = 0; kt < K / 32; ++kt)
            wf[p][kt] = *(const short8*)(Wt + (col0 + p * 16 + lrow) * K + kt * 32 + lk * 8);
    }

    int T = blockIdx.x;
    if (T >= tot) return;

    auto loadx = [&](int TT, short8* xf) {
        const int half = TT >= NTILES;
        const void* A = half ? A1 : A0;
        const int row = (TT - half * NTILES) * 32 + rs * 16 + lrow;
        if constexpr (AF32) {
            const float* X = (const float*)A + (size_t)row * K;
#pragma unroll
            for (int kt = 0; kt < K / 32; ++kt) {
                f32x4 f0 = *(const f32x4*)(X + kt * 32 + lk * 8);
                f32x4 f1 = *(const f32x4*)(X + kt * 32 + lk * 8 + 4);
                short8 v;
#pragma unroll
                for (int e = 0; e < 4; ++e) { v[e] = (short)f2b(f0[e]); v[4 + e] = (short)f2b(f1[e]); }
                xf[kt] = v;
            }
        } else {
            const unsigned short* X = (const unsigned short*)A + (size_t)row * K;
#pragma unroll
            for (int kt = 0; kt < K / 32; ++kt)
                xf[kt] = *(const short8*)(X + kt * 32 + lk * 8);
        }
    };

    short8 xf[K / 32], xn[K / 32];
    loadx(T, xf);
    for (;;) {
        const int Tn = T + gridDim.x;
        const bool more = Tn < tot;
        if (more) loadx(Tn, xn);

        const int half = T >= NTILES;
        unsigned short* Y = half ? Y1 : Y0;
        const int row = (T - half * NTILES) * 32 + rs * 16 + lrow;
#pragma unroll
        for (int p = 0; p < 2; ++p) {
            f32x4 acc = {0.f, 0.f, 0.f, 0.f};
#pragma unroll
            for (int kt = 0; kt < K / 32; ++kt)
                acc = __builtin_amdgcn_mfma_f32_16x16x32_bf16(wf[p][kt], xf[kt], acc, 0, 0, 0);
            float v0 = acc[0] + bv[p][0]; v0 = v0 > 0.f ? v0 : 0.f;
            float v1 = acc[1] + bv[p][1]; v1 = v1 > 0.f ? v1 : 0.f;
            float v2 = acc[2] + bv[p][2]; v2 = v2 > 0.f ? v2 : 0.f;
            float v3 = acc[3] + bv[p][3]; v3 = v3 > 0.f ? v3 : 0.f;
            u32x2 ov = {(unsigned)f2b(v0) | ((unsigned)f2b(v1) << 16),
                        (unsigned)f2b(v2) | ((unsigned)f2b(v3) << 16)};
            *(u32x2*)(Y + (size_t)row * HID + col0 + p * 16 + lk * 4) = ov;
        }
        if (!more) break;
#pragma unroll
        for (int kt = 0; kt < K / 32; ++kt) xf[kt] = xn[kt];
        T = Tn;
    }
}

// aggr6: ONE WAVE PER DEST ROW. 64 lanes x 4B cover the full 256B row, so
// every gather load is coalesced (4 lines) and the neighbor index is
// wave-uniform -> scalar (s_load) index fetch + SGPR-based addressing.
// grid bid = chunk*8 + b (b<->XCD affinity); block = 8 waves x 8 iters = 64 rows.
__global__ __launch_bounds__(512) void aggr6(
    const unsigned short* __restrict__ SE, const unsigned short* __restrict__ IE,
    const int* __restrict__ sidx, const int* __restrict__ iidx,
    unsigned short* __restrict__ G) {
    const int t = threadIdx.x;
    const int wv = t >> 6, lane = t & 63;
    const int b = blockIdx.x & 7;
    const int n0 = (blockIdx.x >> 3) * 64;
    const size_t base = (size_t)b * NNODE * HID;
    const int col = lane * 2;             // 2 bf16 per lane

    const unsigned short* Sb = SE + base + col;
    const unsigned short* Ib = IE + base + col;

    for (int it = 0; it < 8; ++it) {
        const int n = n0 + it * 8 + wv;   // wave-uniform
        if (n >= NNODE) break;
        const int* si = sidx + n * KN;    // uniform addr -> scalar loads
        const int* ii = iidx + n * KN;

        float a0 = 0.f, a1 = 0.f;
        unsigned v[KN];
#pragma unroll
        for (int k = 0; k < KN; ++k)
            v[k] = *(const unsigned*)(Sb + (size_t)si[k] * HID);
#pragma unroll
        for (int k = 0; k < KN; ++k) {
            a0 += __uint_as_float(v[k] << 16);
            a1 += __uint_as_float(v[k] & 0xffff0000u);
        }
#pragma unroll
        for (int k = 0; k < KN; ++k)
            v[k] = *(const unsigned*)(Ib + (size_t)ii[k] * HID);
#pragma unroll
        for (int k = 0; k < KN; ++k) {
            a0 += __uint_as_float(v[k] << 16);
            a1 += __uint_as_float(v[k] & 0xffff0000u);
        }
        const unsigned ov = (unsigned)f2b(a0) | ((unsigned)f2b(a1) << 16);
        *(unsigned*)(G + base + (size_t)n * HID + col) = ov;
    }
}

// Stage B: Y = relu([G|H] @ Wut^T + bu), transposed-operand, persistent W.
__global__ __launch_bounds__(512) void update_gemm2(
    const unsigned short* __restrict__ G, const unsigned short* __restrict__ H,
    const unsigned short* __restrict__ Wut, const float* __restrict__ bu,
    float* __restrict__ Yf, unsigned short* __restrict__ Yb, int writeb) {
    const int t = threadIdx.x, w = t >> 6, lane = t & 63;
    const int lrow = lane & 15, lk = lane >> 4;
    const int rs = w & 1, ng = w >> 1;
    const int col0 = ng * 32;

    short8 wf[2][8];
    f32x4 bv[2];
#pragma unroll
    for (int p = 0; p < 2; ++p) {
        bv[p] = *(const f32x4*)(bu + col0 + p * 16 + lk * 4);
#pragma unroll
        for (int kt = 0; kt < 8; ++kt)
            wf[p][kt] = *(const short8*)(Wut + (col0 + p * 16 + lrow) * 256 + kt * 32 + lk * 8);
    }

    for (int T = blockIdx.x; T < NTILES; T += gridDim.x) {
        const int row = T * 32 + rs * 16 + lrow;
        short8 xf[8];
#pragma unroll
        for (int kt = 0; kt < 4; ++kt) {
            xf[kt]     = *(const short8*)(G + (size_t)row * HID + kt * 32 + lk * 8);
            xf[4 + kt] = *(const short8*)(H + (size_t)row * HID + kt * 32 + lk * 8);
        }
#pragma unroll
        for (int p = 0; p < 2; ++p) {
            f32x4 acc = {0.f, 0.f, 0.f, 0.f};
#pragma unroll
            for (int kt = 0; kt < 8; ++kt)
                acc = __builtin_amdgcn_mfma_f32_16x16x32_bf16(wf[p][kt], xf[kt], acc, 0, 0, 0);
            f32x4 o;
#pragma unroll
            for (int j = 0; j < 4; ++j) {
                float v = acc[j] + bv[p][j];
                o[j] = v > 0.f ? v : 0.f;
            }
            *(f32x4*)(Yf + (size_t)row * HID + col0 + p * 16 + lk * 4) = o;
            if (writeb) {
                u32x2 ov = {(unsigned)f2b(o[0]) | ((unsigned)f2b(o[1]) << 16),
                            (unsigned)f2b(o[2]) | ((unsigned)f2b(o[3]) << 16)};
                *(u32x2*)(Yb + (size_t)row * HID + col0 + p * 16 + lk * 4) = ov;
            }
        }
    }
}

extern "C" void kernel_launch(void* const* d_in, const int* in_sizes, int n_in,
                              void* d_out, int out_size, void* d_ws, size_t ws_size,
                              hipStream_t stream) {
    const float* state    = (const float*)d_in[0];
    const float* internal = (const float*)d_in[1];
    const int*   sidx     = (const int*)d_in[2];
    const int*   iidx     = (const int*)d_in[3];
    const float* W1  = (const float*)d_in[4];
    const float* b1  = (const float*)d_in[5];
    const float* W2  = (const float*)d_in[6];
    const float* b2  = (const float*)d_in[7];
    const float* Wu1 = (const float*)d_in[8];
    const float* bu1 = (const float*)d_in[9];
    const float* Wu2 = (const float*)d_in[10];
    const float* bu2 = (const float*)d_in[11];

    float* hu1 = (float*)d_out;
    float* hu2 = hu1 + (size_t)ROWS * HID;

    unsigned short* W1t  = (unsigned short*)d_ws;          // [128][64]
    unsigned short* W2t  = W1t  + 64 * 128;                // [128][128]
    unsigned short* Wu1t = W2t  + 128 * 128;               // [128][256]
    unsigned short* Wu2t = Wu1t + 256 * 128;               // [128][256]
    unsigned short* bufA = Wu2t + 256 * 128;               // [ROWS][128] bf16 each
    unsigned short* bufB = bufA + (size_t)ROWS * HID;
    unsigned short* bufC = bufB + (size_t)ROWS * HID;
    unsigned short* bufD = bufC + (size_t)ROWS * HID;

    const size_t need4 = (size_t)90112 * 2 + 4 * (size_t)ROWS * HID * 2;
    const bool big = ws_size >= need4;

    dim3 b256(256), b512(512);
    const int AGRID = 157 * 8;   // 1256 blocks, 64 rows each

    wconv_all<<<352, b256, 0, stream>>>(W1, W2, Wu1, Wu2, W1t, W2t, Wu1t, Wu2t);

    // layer-1 embeddings: SE1 -> bufA, IE1 -> bufB
    embed2<64, true><<<1250, b512, 0, stream>>>(state, internal, W1t, b1, bufA, bufB, 2 * NTILES);

    if (big) {
        // aggr1 -> bufD; hu1 = relu([aggr1|IE1]@Wu1+bu1) -> d_out + bufC
        aggr6<<<AGRID, b512, 0, stream>>>(bufA, bufB, sidx, iidx, bufD);
        update_gemm2<<<1250, b512, 0, stream>>>(bufD, bufB, Wu1t, bu1, hu1, bufC, 1);
        // se2: bufA -> bufB; ie2: bufC -> bufD (one launch, disjoint)
        embed2<128, false><<<1250, b512, 0, stream>>>(bufA, bufC, W2t, b2, bufB, bufD, 2 * NTILES);
        // aggr2 -> bufA; hu2 = relu([aggr2|ie2]@Wu2+bu2) -> d_out
        aggr6<<<AGRID, b512, 0, stream>>>(bufB, bufD, sidx, iidx, bufA);
        update_gemm2<<<1250, b512, 0, stream>>>(bufA, bufD, Wu2t, bu2, hu2, nullptr, 0);
    } else {
        // 3-buffer fallback: use the hu2 region (written last) as bf16 scratch.
        unsigned short* Ghu2 = (unsigned short*)hu2;
        aggr6<<<AGRID, b512, 0, stream>>>(bufA, bufB, sidx, iidx, Ghu2);
        update_gemm2<<<1250, b512, 0, stream>>>(Ghu2, bufB, Wu1t, bu1, hu1, bufC, 1);
        embed2<128, false><<<1250, b512, 0, stream>>>(bufA, nullptr, W2t, b2, bufB, nullptr, NTILES);
        embed2<128, false><<<1250, b512, 0, stream>>>(bufC, nullptr, W2t, b2, bufA, nullptr, NTILES);
        aggr6<<<AGRID, b512, 0, stream>>>(bufB, bufA, sidx, iidx, bufC);
        update_gemm2<<<1250, b512, 0, stream>>>(bufC, bufA, Wu2t, bu2, hu2, nullptr, 0);
    }
}